// Round 10
// baseline (150.016 us; speedup 1.0000x reference)
//
#include <hip/hip_runtime.h>
#include <stdint.h>

typedef unsigned short u16;
typedef unsigned int u32;

#define L_SEQ 2048
#define DMODEL 1024
#define NHEAD 16
#define NSPLIT 2

using f32x4 = __attribute__((ext_vector_type(4))) float;
using s16x8 = __attribute__((ext_vector_type(8))) short;
using s16x4 = __attribute__((ext_vector_type(4))) short;

__device__ __forceinline__ u16 f2b(float f) {
    union { float f; uint32_t u; } v; v.f = f;
    uint32_t r = v.u + 0x7fffu + ((v.u >> 16) & 1u);
    return (u16)(r >> 16);
}

__device__ __forceinline__ float b2f(u16 x) {
    union { uint32_t u; float f; } v; v.u = ((uint32_t)x) << 16;
    return v.f;
}

__device__ __forceinline__ void gld16(const void* g, void* l) {
    __builtin_amdgcn_global_load_lds(
        (__attribute__((address_space(1))) void*)(uintptr_t)g,
        (__attribute__((address_space(3))) void*)(uintptr_t)l,
        16, 0, 0);
}

// ---------------- merged: f32->bf16 converts + phase features ----------------
__global__ __launch_bounds__(256)
void k_pre(const float* __restrict__ x, const float* __restrict__ wq,
           const float* __restrict__ wk, const float* __restrict__ wv,
           const float* __restrict__ wo,
           u16* __restrict__ xb, u16* __restrict__ wqb, u16* __restrict__ wkb,
           u16* __restrict__ wvb, u16* __restrict__ wob,
           const float* __restrict__ Wp, const float* __restrict__ bp,
           float2* __restrict__ CSph) {
    const int NX = L_SEQ * DMODEL / 8;     // 262144
    const int NW = DMODEL * DMODEL / 8;    // 131072 = 2^17
    const int NCONV = (NX + 4 * NW) / 256; // 3072 blocks
    const int tid = threadIdx.x;
    __shared__ float pbuf[4][32];

    if ((int)blockIdx.x < NCONV) {
        int i = blockIdx.x * 256 + tid;
        const float* src; u16* dst; int j;
        if (i < NX) { src = x; dst = xb; j = i; }
        else {
            int t = i - NX; int sel = t >> 17; j = t & (NW - 1);
            src = (sel == 0) ? wq : (sel == 1) ? wk : (sel == 2) ? wv : wo;
            dst = (sel == 0) ? wqb : (sel == 1) ? wkb : (sel == 2) ? wvb : wob;
        }
        const float4* s4 = (const float4*)src;
        float4 a = s4[2 * j], b = s4[2 * j + 1];
        union { s16x8 v; u16 u[8]; } o;
        o.u[0] = f2b(a.x); o.u[1] = f2b(a.y); o.u[2] = f2b(a.z); o.u[3] = f2b(a.w);
        o.u[4] = f2b(b.x); o.u[5] = f2b(b.y); o.u[6] = f2b(b.z); o.u[7] = f2b(b.w);
        ((s16x8*)dst)[j] = o.v;
        return;
    }

    const int w = tid >> 6, lane = tid & 63;
    const int m = (blockIdx.x - NCONV) * 4 + w;
    float xr[16];
#pragma unroll
    for (int i = 0; i < 16; ++i) xr[i] = x[(size_t)m * DMODEL + lane + 64 * i];
#pragma unroll 4
    for (int n = 0; n < 32; ++n) {
        const float* wrow = Wp + n * DMODEL;
        float s = 0.f;
#pragma unroll
        for (int i = 0; i < 16; ++i) s += xr[i] * wrow[lane + 64 * i];
#pragma unroll
        for (int msk = 32; msk >= 1; msk >>= 1) s += __shfl_xor(s, msk);
        if (lane == 0) pbuf[w][n] = s + bp[n];
    }
    __syncthreads();
    if (lane < 16) {
        float c = pbuf[w][2 * lane], sn = pbuf[w][2 * lane + 1];
        float nrm = sqrtf(c * c + sn * sn);
        float inv = 1.0f / fmaxf(nrm, 1e-6f);
        CSph[(size_t)lane * L_SEQ + m] = make_float2(c * inv, sn * inv);
    }
}

// ---------------- bf16 B^T GEMM, BM=128 BN=64 BK=64, XOR-swizzled LDS (verified R9) ----------------
// MODE 0: bf16 out; V segment (seg==2) written TRANSPOSED to Vt[feat][token].
// MODE 1: f32 out.
template <int MODE>
__global__ __launch_bounds__(256, 2)
void k_gemm64(const u16* __restrict__ A,
              const u16* __restrict__ B0, const u16* __restrict__ B1, const u16* __restrict__ B2,
              const float* __restrict__ c0, const float* __restrict__ c1, const float* __restrict__ c2,
              void* __restrict__ Out, u16* __restrict__ Vt, int ldo, int K) {
    __shared__ u16 As[128 * 64];
    __shared__ u16 Bs[64 * 64];
    const int tid = threadIdx.x;
    const int w = tid >> 6, lane = tid & 63;
    const int wr = w >> 1, wc = w & 1;
    const int u = lane & 15, g = lane >> 4;
    const int lr = lane >> 3;
    const int cb = lane & 7;
    const int mt = blockIdx.x, nt = blockIdx.y;
    const int seg = nt >> 4, ntl = nt & 15;
    const u16* Bp = (seg == 0) ? B0 : (seg == 1) ? B1 : B2;
    const float* biasp = (seg == 0) ? c0 : (seg == 1) ? c1 : c2;

    const u16* Ab = A + (size_t)(mt * 128 + w * 32) * K;
    const u16* Bb = Bp + (size_t)(ntl * 64) * K;
    char* asB = (char*)As;
    char* bsB = (char*)Bs;

    f32x4 acc[4][2] = {};

    for (int k0 = 0; k0 < K; k0 += 64) {
#pragma unroll
        for (int c = 0; c < 4; ++c)
            gld16(Ab + (size_t)(c * 8 + lr) * K + k0 + ((cb ^ lr) * 8),
                  asB + (w * 32 + c * 8) * 128);
#pragma unroll
        for (int t = 0; t < 2; ++t)
            gld16(Bb + (size_t)(t * 32 + w * 8 + lr) * K + k0 + ((cb ^ lr) * 8),
                  bsB + t * 4096 + w * 1024);
        __syncthreads();
        const int x0 = (g * 16) ^ ((u & 7) << 4);
#pragma unroll
        for (int ks = 0; ks < 2; ++ks) {
            s16x8 af[4], bf[2];
#pragma unroll
            for (int i = 0; i < 4; ++i)
                af[i] = *(const s16x8*)(asB + (wr * 64 + i * 16 + u) * 128 + (x0 ^ (ks * 64)));
#pragma unroll
            for (int j = 0; j < 2; ++j)
                bf[j] = *(const s16x8*)(bsB + (wc * 32 + j * 16 + u) * 128 + (x0 ^ (ks * 64)));
#pragma unroll
            for (int i = 0; i < 4; ++i)
#pragma unroll
                for (int j = 0; j < 2; ++j)
                    acc[i][j] = __builtin_amdgcn_mfma_f32_16x16x32_bf16(af[i], bf[j], acc[i][j], 0, 0, 0);
        }
        __syncthreads();
    }

#pragma unroll
    for (int i = 0; i < 4; ++i) {
#pragma unroll
        for (int j = 0; j < 2; ++j) {
            const int row0 = mt * 128 + wr * 64 + i * 16 + g * 4;
            const int col = nt * 64 + wc * 32 + j * 16 + u;
            const int colseg = ntl * 64 + wc * 32 + j * 16 + u;
            const float bias = biasp[colseg];
            if (MODE == 0 && seg == 2) {
                // V: write transposed -> Vt[feat][token], 8B packed store
                union { s16x4 v; u16 us[4]; } p;
#pragma unroll
                for (int r = 0; r < 4; ++r) p.us[r] = f2b(acc[i][j][r] + bias);
                *(s16x4*)(Vt + (size_t)colseg * L_SEQ + row0) = p.v;
            } else {
#pragma unroll
                for (int r = 0; r < 4; ++r) {
                    float val = acc[i][j][r] + bias;
                    if (MODE == 1)
                        ((float*)Out)[(size_t)(row0 + r) * ldo + col] = val;
                    else
                        ((u16*)Out)[(size_t)(row0 + r) * ldo + col] = f2b(val);
                }
            }
        }
    }
}

// ---------------- fused attention, key-split (R6 structure verbatim, NT halved) ----------------
// grid (L/64, H, NSPLIT). Split s handles keys [s*1024, s*1024+1024).
// Writes unnormalized O (bf16) + (m,l) partials; k_comb merges.
__global__ __launch_bounds__(256, 4)
void k_attn(const u16* __restrict__ QKV, const u16* __restrict__ VtG,
            const float2* __restrict__ CSph,
            const float* __restrict__ gamma,
            u16* __restrict__ Op, float2* __restrict__ ML) {
    const int h = blockIdx.y;
    const int s = blockIdx.z;
    const int qb = blockIdx.x * 64;
    const int tid = threadIdx.x;
    const int w = tid >> 6, lane = tid & 63;
    const int u = lane & 15, g = lane >> 4;
    const int ld = 3 * DMODEL;
    const int NT = L_SEQ / 64 / NSPLIT;   // 16
    const int BUF = 64 * 64 * 2;
    const int kbase = s * (L_SEQ / NSPLIT);

    __shared__ u16 Ks[2][64 * 64];
    __shared__ u16 Vs[2][64 * 64];
    __shared__ u16 Pl[4][16 * 64];

    const float LOG2E = 1.44269504088896f;
    const float gate2 = (0.08f / (1.0f + __expf(-gamma[h]))) * LOG2E;
    const float SC2 = 0.125f * LOG2E;

    const u16* Qp = QKV + h * 64;
    const u16* Kp = QKV + DMODEL + h * 64 + (size_t)kbase * ld;
    const u16* VtH = VtG + (size_t)h * 64 * L_SEQ + kbase;
    const float2* CS = CSph + (size_t)h * L_SEQ;

    s16x8 aq0, aq1;
    {
        const int qrow = qb + w * 16 + u;
        aq0 = *(const s16x8*)(Qp + (size_t)qrow * ld + g * 8);
        aq1 = *(const s16x8*)(Qp + (size_t)qrow * ld + 32 + g * 8);
    }
    float gcq[4], gsq[4];
#pragma unroll
    for (int r = 0; r < 4; ++r) {
        float2 cs = CS[qb + w * 16 + g * 4 + r];
        gcq[r] = gate2 * cs.x;
        gsq[r] = gate2 * cs.y;
    }

    union { u16 us[8]; s16x8 v; } one_;
#pragma unroll
    for (int i = 0; i < 8; ++i) one_.us[i] = 0x3F80;   // bf16 1.0
    const s16x8 vone = one_.v;

    unsigned dstOff[2];
    size_t srcK[2], srcV[2];
#pragma unroll
    for (int t = 0; t < 2; ++t) {
        int ci = (w * 2 + t) * 64 + lane;
        int row = ci >> 3, cb = ci & 7;
        dstOff[t] = (unsigned)((w * 2 + t) * 1024);
        srcK[t] = (size_t)row * ld + (size_t)((cb ^ (row & 7)) * 8);
        srcV[t] = (size_t)row * L_SEQ + (size_t)((cb ^ (row & 7)) * 8);
    }
    char* ksBase = (char*)Ks;
    char* vsBase = (char*)Vs;
    char* PlB = (char*)Pl + w * 2048;

#pragma unroll
    for (int t = 0; t < 2; ++t) {
        gld16(Kp + srcK[t], ksBase + dstOff[t]);
        gld16(VtH + srcV[t], vsBase + dstOff[t]);
    }
    __syncthreads();

    float mrow[4];
    f32x4 lacc = {};
    f32x4 oacc[4] = {};
#pragma unroll
    for (int r = 0; r < 4; ++r) mrow[r] = -1e30f;

    float2 cskN[4];
#pragma unroll
    for (int kb = 0; kb < 4; ++kb) cskN[kb] = CS[kbase + kb * 16 + u];

    for (int kt = 0; kt < NT; ++kt) {
        const int cur = kt & 1;
        const char* kCur = ksBase + cur * BUF;
        const char* vCur = vsBase + cur * BUF;

        s16x8 vbr[4][2];
#pragma unroll
        for (int ks = 0; ks < 2; ++ks) {
            const int xv = (ks * 64 + g * 16) ^ ((u & 7) << 4);
#pragma unroll
            for (int db = 0; db < 4; ++db)
                vbr[db][ks] = *(const s16x8*)(vCur + (db * 16 + u) * 128 + xv);
        }

        float ck4[4], sk4[4];
#pragma unroll
        for (int kb = 0; kb < 4; ++kb) { ck4[kb] = cskN[kb].x; sk4[kb] = cskN[kb].y; }
        if (kt + 1 < NT) {
#pragma unroll
            for (int kb = 0; kb < 4; ++kb)
                cskN[kb] = CS[kbase + (kt + 1) * 64 + kb * 16 + u];
        }

        if (kt + 1 < NT) {
            const u16* Kn = Kp + (size_t)(kt + 1) * 64 * ld;
            const u16* Vn = VtH + (size_t)(kt + 1) * 64;
            char* kN = ksBase + (cur ^ 1) * BUF;
            char* vN = vsBase + (cur ^ 1) * BUF;
#pragma unroll
            for (int t = 0; t < 2; ++t) {
                gld16(Kn + srcK[t], kN + dstOff[t]);
                gld16(Vn + srcV[t], vN + dstOff[t]);
            }
        }

        // ---- S = Q K^T ----
        f32x4 sf[4] = {};
        const int x0 = (g * 16) ^ ((u & 7) << 4);
#pragma unroll
        for (int kb = 0; kb < 4; ++kb) {
            const int rowb = (kb * 16 + u) * 128;
            s16x8 b0 = *(const s16x8*)(kCur + rowb + x0);
            s16x8 b1 = *(const s16x8*)(kCur + rowb + (x0 ^ 64));
            sf[kb] = __builtin_amdgcn_mfma_f32_16x16x32_bf16(aq0, b0, sf[kb], 0, 0, 0);
            sf[kb] = __builtin_amdgcn_mfma_f32_16x16x32_bf16(aq1, b1, sf[kb], 0, 0, 0);
        }

        // ---- bias + lane-local max ----
        float sv[4][4], tmax[4];
#pragma unroll
        for (int r = 0; r < 4; ++r) tmax[r] = -1e30f;
#pragma unroll
        for (int kb = 0; kb < 4; ++kb)
#pragma unroll
            for (int r = 0; r < 4; ++r) {
                float xv = sf[kb][r] * SC2 + gcq[r] * ck4[kb] + gsq[r] * sk4[kb];
                sv[kb][r] = xv;
                tmax[r] = fmaxf(tmax[r], xv);
            }

        // ---- deferred max ----
        bool need = false;
#pragma unroll
        for (int r = 0; r < 4; ++r) need |= (tmax[r] > mrow[r] + 4.0f);
        if (__any(need)) {
            float scl[4];
#pragma unroll
            for (int r = 0; r < 4; ++r) {
                float t = tmax[r];
#pragma unroll
                for (int msk = 1; msk <= 8; msk <<= 1)
                    t = fmaxf(t, __shfl_xor(t, msk));
                float mn = fmaxf(mrow[r], t);
                scl[r] = __builtin_amdgcn_exp2f(mrow[r] - mn);
                mrow[r] = mn;
            }
#pragma unroll
            for (int db = 0; db < 4; ++db)
#pragma unroll
                for (int r = 0; r < 4; ++r)
                    oacc[db][r] *= scl[r];
#pragma unroll
            for (int r = 0; r < 4; ++r) lacc[r] *= scl[r];
        }

        // ---- P = exp2(S - m) -> LDS ----
#pragma unroll
        for (int kb = 0; kb < 4; ++kb)
#pragma unroll
            for (int r = 0; r < 4; ++r) {
                float p = __builtin_amdgcn_exp2f(sv[kb][r] - mrow[r]);
                int prow = g * 4 + r;
                int pb = prow * 128 + (kb * 16 + u) * 2;
                pb ^= (prow & 7) << 4;
                *(u16*)(PlB + pb) = f2b(p);
            }

        // ---- O += P V ; l += P * ones ----
#pragma unroll
        for (int ks = 0; ks < 2; ++ks) {
            s16x8 pa = *(const s16x8*)(PlB + u * 128 + ((ks * 64 + g * 16) ^ ((u & 7) << 4)));
            lacc = __builtin_amdgcn_mfma_f32_16x16x32_bf16(pa, vone, lacc, 0, 0, 0);
#pragma unroll
            for (int db = 0; db < 4; ++db)
                oacc[db] = __builtin_amdgcn_mfma_f32_16x16x32_bf16(pa, vbr[db][ks], oacc[db], 0, 0, 0);
        }
        __syncthreads();
    }

    // ---- write partials ----
    u16* OpS = Op + (size_t)s * L_SEQ * DMODEL;
    float2* MLS = ML + (size_t)(s * NHEAD + h) * L_SEQ;
#pragma unroll
    for (int db = 0; db < 4; ++db)
#pragma unroll
        for (int r = 0; r < 4; ++r) {
            int qr = qb + w * 16 + g * 4 + r;
            int col = h * 64 + db * 16 + u;
            OpS[(size_t)qr * DMODEL + col] = f2b(oacc[db][r]);
        }
    if (u == 0) {
#pragma unroll
        for (int r = 0; r < 4; ++r) {
            int qr = qb + w * 16 + g * 4 + r;
            MLS[qr] = make_float2(mrow[r], lacc[r]);
        }
    }
}

// ---------------- split combine: attnb = (a0*O0 + a1*O1) / (a0*l0 + a1*l1) ----------------
__global__ __launch_bounds__(256)
void k_comb(const u16* __restrict__ Op, const float2* __restrict__ ML,
            u16* __restrict__ attnb) {
    int t = blockIdx.x * 256 + threadIdx.x;   // 262144 total
    int row = t >> 7, cg = t & 127;
    int col0 = cg * 8, h = cg >> 3;
    float2 ml0 = ML[(size_t)h * L_SEQ + row];
    float2 ml1 = ML[(size_t)(NHEAD + h) * L_SEQ + row];
    float M = fmaxf(ml0.x, ml1.x);
    float a0 = __builtin_amdgcn_exp2f(ml0.x - M);
    float a1 = __builtin_amdgcn_exp2f(ml1.x - M);
    float inv = 1.0f / (ml0.y * a0 + ml1.y * a1);
    a0 *= inv; a1 *= inv;
    union { s16x8 v; u16 us[8]; } o0, o1, wout;
    o0.v = *(const s16x8*)(Op + (size_t)row * DMODEL + col0);
    o1.v = *(const s16x8*)(Op + (size_t)L_SEQ * DMODEL + (size_t)row * DMODEL + col0);
#pragma unroll
    for (int j = 0; j < 8; ++j)
        wout.us[j] = f2b(b2f(o0.us[j]) * a0 + b2f(o1.us[j]) * a1);
    *(s16x8*)(attnb + (size_t)row * DMODEL + col0) = wout.v;
}

extern "C" void kernel_launch(void* const* d_in, const int* in_sizes, int n_in,
                              void* d_out, int out_size, void* d_ws, size_t ws_size,
                              hipStream_t stream) {
    const float* x  = (const float*)d_in[0];
    const float* Wq = (const float*)d_in[1];
    const float* bq = (const float*)d_in[2];
    const float* Wk = (const float*)d_in[3];
    const float* bk = (const float*)d_in[4];
    const float* Wv = (const float*)d_in[5];
    const float* bv = (const float*)d_in[6];
    const float* Wo = (const float*)d_in[7];
    const float* bo = (const float*)d_in[8];
    const float* Wp = (const float*)d_in[9];
    const float* bp = (const float*)d_in[10];
    const float* gamma = (const float*)d_in[11];
    float* out = (float*)d_out;

    char* ws = (char*)d_ws;
    u16* xb = (u16*)ws;   ws += (size_t)L_SEQ * DMODEL * 2;       // 4 MB
    u16* wqb = (u16*)ws;  ws += (size_t)DMODEL * DMODEL * 2;      // 2 MB
    u16* wkb = (u16*)ws;  ws += (size_t)DMODEL * DMODEL * 2;      // 2 MB
    u16* wvb = (u16*)ws;  ws += (size_t)DMODEL * DMODEL * 2;      // 2 MB
    u16* wob = (u16*)ws;  ws += (size_t)DMODEL * DMODEL * 2;      // 2 MB
    u16* qkv = (u16*)ws;  ws += (size_t)L_SEQ * 3 * DMODEL * 2;   // 12 MB
    u16* attnb = (u16*)ws; ws += (size_t)L_SEQ * DMODEL * 2;      // 4 MB
    u16* VtG = (u16*)ws;  ws += (size_t)DMODEL * L_SEQ * 2;       // 4 MB
    float2* CSph = (float2*)ws; ws += (size_t)NHEAD * L_SEQ * 8;  // 256 KB

    // overlays: xb/wqb/wkb/wvb are dead after the QKV GEMM.
    u16* Op = xb;                   // 2 x 2048 x 1024 u16 = 8 MB (spans xb+wqb+wkb)
    float2* ML = (float2*)wvb;      // 2 x 16 x 2048 float2 = 512 KB

    // converts (3072 blocks) + phase (512 blocks)
    k_pre<<<3072 + 512, 256, 0, stream>>>(x, Wq, Wk, Wv, Wo, xb, wqb, wkb, wvb, wob,
                                          Wp, bp, CSph);

    // fused QKV projection: Q,K -> qkv bf16; V -> VtG transposed
    k_gemm64<0><<<dim3(16, 48), 256, 0, stream>>>(xb, wqb, wkb, wvb, bq, bk, bv,
                                                  (void*)qkv, VtG, 3 * DMODEL, DMODEL);

    // key-split attention -> partials
    k_attn<<<dim3(L_SEQ / 64, NHEAD, NSPLIT), 256, 0, stream>>>(qkv, VtG, CSph, gamma, Op, ML);

    // merge splits -> attnb bf16
    k_comb<<<L_SEQ * DMODEL / 8 / 256, 256, 0, stream>>>(Op, ML, attnb);

    // output projection -> d_out f32
    k_gemm64<1><<<dim3(16, 16), 256, 0, stream>>>(attnb, wob, wob, wob, bo, bo, bo,
                                                  (void*)out, nullptr, DMODEL, DMODEL);
}

// Round 11
// 111.115 us; speedup vs baseline: 1.3501x; 1.3501x over previous
//
#include <hip/hip_runtime.h>
#include <stdint.h>

typedef unsigned short u16;

#define L_SEQ 2048
#define DMODEL 1024
#define NHEAD 16

using f32x4 = __attribute__((ext_vector_type(4))) float;
using s16x8 = __attribute__((ext_vector_type(8))) short;
using s16x4 = __attribute__((ext_vector_type(4))) short;

__device__ __forceinline__ u16 f2b(float f) {
    union { float f; uint32_t u; } v; v.f = f;
    uint32_t r = v.u + 0x7fffu + ((v.u >> 16) & 1u);
    return (u16)(r >> 16);
}

__device__ __forceinline__ void gld16(const void* g, void* l) {
    __builtin_amdgcn_global_load_lds(
        (__attribute__((address_space(1))) void*)(uintptr_t)g,
        (__attribute__((address_space(3))) void*)(uintptr_t)l,
        16, 0, 0);
}

// ---------------- merged: f32->bf16 converts + phase features ----------------
__global__ __launch_bounds__(256)
void k_pre(const float* __restrict__ x, const float* __restrict__ wq,
           const float* __restrict__ wk, const float* __restrict__ wv,
           const float* __restrict__ wo,
           u16* __restrict__ xb, u16* __restrict__ wqb, u16* __restrict__ wkb,
           u16* __restrict__ wvb, u16* __restrict__ wob,
           const float* __restrict__ Wp, const float* __restrict__ bp,
           float2* __restrict__ CSph) {
    const int NX = L_SEQ * DMODEL / 8;     // 262144
    const int NW = DMODEL * DMODEL / 8;    // 131072 = 2^17
    const int NCONV = (NX + 4 * NW) / 256; // 3072 blocks
    const int tid = threadIdx.x;
    __shared__ float pbuf[4][32];

    if ((int)blockIdx.x < NCONV) {
        int i = blockIdx.x * 256 + tid;
        const float* src; u16* dst; int j;
        if (i < NX) { src = x; dst = xb; j = i; }
        else {
            int t = i - NX; int sel = t >> 17; j = t & (NW - 1);
            src = (sel == 0) ? wq : (sel == 1) ? wk : (sel == 2) ? wv : wo;
            dst = (sel == 0) ? wqb : (sel == 1) ? wkb : (sel == 2) ? wvb : wob;
        }
        const float4* s4 = (const float4*)src;
        float4 a = s4[2 * j], b = s4[2 * j + 1];
        union { s16x8 v; u16 u[8]; } o;
        o.u[0] = f2b(a.x); o.u[1] = f2b(a.y); o.u[2] = f2b(a.z); o.u[3] = f2b(a.w);
        o.u[4] = f2b(b.x); o.u[5] = f2b(b.y); o.u[6] = f2b(b.z); o.u[7] = f2b(b.w);
        ((s16x8*)dst)[j] = o.v;
        return;
    }

    const int w = tid >> 6, lane = tid & 63;
    const int m = (blockIdx.x - NCONV) * 4 + w;
    float xr[16];
#pragma unroll
    for (int i = 0; i < 16; ++i) xr[i] = x[(size_t)m * DMODEL + lane + 64 * i];
#pragma unroll 4
    for (int n = 0; n < 32; ++n) {
        const float* wrow = Wp + n * DMODEL;
        float s = 0.f;
#pragma unroll
        for (int i = 0; i < 16; ++i) s += xr[i] * wrow[lane + 64 * i];
#pragma unroll
        for (int msk = 32; msk >= 1; msk >>= 1) s += __shfl_xor(s, msk);
        if (lane == 0) pbuf[w][n] = s + bp[n];
    }
    __syncthreads();
    if (lane < 16) {
        float c = pbuf[w][2 * lane], sn = pbuf[w][2 * lane + 1];
        float nrm = sqrtf(c * c + sn * sn);
        float inv = 1.0f / fmaxf(nrm, 1e-6f);
        CSph[(size_t)lane * L_SEQ + m] = make_float2(c * inv, sn * inv);
    }
}

// ---------------- bf16 B^T GEMM, BM=128 BN=64 BK=64 (verified R9/R10) ----------------
// MODE 0: bf16 out; V segment (seg==2) written TRANSPOSED to Vt[feat][token] (verified R10).
// MODE 1: f32 out.
template <int MODE>
__global__ __launch_bounds__(256, 2)
void k_gemm64(const u16* __restrict__ A,
              const u16* __restrict__ B0, const u16* __restrict__ B1, const u16* __restrict__ B2,
              const float* __restrict__ c0, const float* __restrict__ c1, const float* __restrict__ c2,
              void* __restrict__ Out, u16* __restrict__ Vt, int ldo, int K) {
    __shared__ u16 As[128 * 64];
    __shared__ u16 Bs[64 * 64];
    const int tid = threadIdx.x;
    const int w = tid >> 6, lane = tid & 63;
    const int wr = w >> 1, wc = w & 1;
    const int u = lane & 15, g = lane >> 4;
    const int lr = lane >> 3;
    const int cb = lane & 7;
    const int mt = blockIdx.x, nt = blockIdx.y;
    const int seg = nt >> 4, ntl = nt & 15;
    const u16* Bp = (seg == 0) ? B0 : (seg == 1) ? B1 : B2;
    const float* biasp = (seg == 0) ? c0 : (seg == 1) ? c1 : c2;

    const u16* Ab = A + (size_t)(mt * 128 + w * 32) * K;
    const u16* Bb = Bp + (size_t)(ntl * 64) * K;
    char* asB = (char*)As;
    char* bsB = (char*)Bs;

    f32x4 acc[4][2] = {};

    for (int k0 = 0; k0 < K; k0 += 64) {
#pragma unroll
        for (int c = 0; c < 4; ++c)
            gld16(Ab + (size_t)(c * 8 + lr) * K + k0 + ((cb ^ lr) * 8),
                  asB + (w * 32 + c * 8) * 128);
#pragma unroll
        for (int t = 0; t < 2; ++t)
            gld16(Bb + (size_t)(t * 32 + w * 8 + lr) * K + k0 + ((cb ^ lr) * 8),
                  bsB + t * 4096 + w * 1024);
        __syncthreads();
        const int x0 = (g * 16) ^ ((u & 7) << 4);
#pragma unroll
        for (int ks = 0; ks < 2; ++ks) {
            s16x8 af[4], bf[2];
#pragma unroll
            for (int i = 0; i < 4; ++i)
                af[i] = *(const s16x8*)(asB + (wr * 64 + i * 16 + u) * 128 + (x0 ^ (ks * 64)));
#pragma unroll
            for (int j = 0; j < 2; ++j)
                bf[j] = *(const s16x8*)(bsB + (wc * 32 + j * 16 + u) * 128 + (x0 ^ (ks * 64)));
#pragma unroll
            for (int i = 0; i < 4; ++i)
#pragma unroll
                for (int j = 0; j < 2; ++j)
                    acc[i][j] = __builtin_amdgcn_mfma_f32_16x16x32_bf16(af[i], bf[j], acc[i][j], 0, 0, 0);
        }
        __syncthreads();
    }

#pragma unroll
    for (int i = 0; i < 4; ++i) {
#pragma unroll
        for (int j = 0; j < 2; ++j) {
            const int row0 = mt * 128 + wr * 64 + i * 16 + g * 4;
            const int col = nt * 64 + wc * 32 + j * 16 + u;
            const int colseg = ntl * 64 + wc * 32 + j * 16 + u;
            const float bias = biasp[colseg];
            if (MODE == 0 && seg == 2) {
                union { s16x4 v; u16 us[4]; } p;
#pragma unroll
                for (int r = 0; r < 4; ++r) p.us[r] = f2b(acc[i][j][r] + bias);
                *(s16x4*)(Vt + (size_t)colseg * L_SEQ + row0) = p.v;
            } else {
#pragma unroll
                for (int r = 0; r < 4; ++r) {
                    float val = acc[i][j][r] + bias;
                    if (MODE == 1)
                        ((float*)Out)[(size_t)(row0 + r) * ldo + col] = val;
                    else
                        ((u16*)Out)[(size_t)(row0 + r) * ldo + col] = f2b(val);
                }
            }
        }
    }
}

// ---------------- fused attention v7: KVBLK=128 as two verified 64-key sub-tiles ----------------
// grid (L/64, H), 4 waves x 16 q-rows. Per iteration: one barrier pair covers
// TWO 64-key sub-tiles (all LDS layouts byte-identical per sub-tile to the
// verified R6/R9 kernel). Barriers and defer-checks halve per key.
__global__ __launch_bounds__(256, 2)
void k_attn(const u16* __restrict__ QKV, const u16* __restrict__ VtG,
            const float2* __restrict__ CSph,
            const float* __restrict__ gamma, u16* __restrict__ Oout) {
    const int h = blockIdx.y;
    const int qb = blockIdx.x * 64;
    const int tid = threadIdx.x;
    const int w = tid >> 6, lane = tid & 63;
    const int u = lane & 15, g = lane >> 4;
    const int ld = 3 * DMODEL;
    const int NT = L_SEQ / 128;           // 16 iterations
    const int SUB = 64 * 64 * 2;          // 8192 B per sub-tile
    const int BUF = 2 * SUB;              // 16384 B per dbuf slot

    __shared__ u16 Ks[2][2][64 * 64];     // [cur][sub]
    __shared__ u16 Vs[2][2][64 * 64];     // [cur][sub] (V^T: row=d, col=key)
    __shared__ u16 Pl[4][16 * 64];

    const float LOG2E = 1.44269504088896f;
    const float gate2 = (0.08f / (1.0f + __expf(-gamma[h]))) * LOG2E;
    const float SC2 = 0.125f * LOG2E;

    const u16* Qp = QKV + h * 64;
    const u16* Kp = QKV + DMODEL + h * 64;
    const u16* VtH = VtG + (size_t)h * 64 * L_SEQ;
    const float2* CS = CSph + (size_t)h * L_SEQ;

    s16x8 aq0, aq1;
    {
        const int qrow = qb + w * 16 + u;
        aq0 = *(const s16x8*)(Qp + (size_t)qrow * ld + g * 8);
        aq1 = *(const s16x8*)(Qp + (size_t)qrow * ld + 32 + g * 8);
    }
    float gcq[4], gsq[4];
#pragma unroll
    for (int r = 0; r < 4; ++r) {
        float2 cs = CS[qb + w * 16 + g * 4 + r];
        gcq[r] = gate2 * cs.x;
        gsq[r] = gate2 * cs.y;
    }

    union { u16 us[8]; s16x8 v; } one_;
#pragma unroll
    for (int i = 0; i < 8; ++i) one_.us[i] = 0x3F80;   // bf16 1.0
    const s16x8 vone = one_.v;

    // per-sub-tile staging addresses (verified R6/R9 pattern)
    unsigned dstOff[2];
    size_t srcK[2], srcV[2];
#pragma unroll
    for (int t = 0; t < 2; ++t) {
        int ci = (w * 2 + t) * 64 + lane;
        int row = ci >> 3, cb = ci & 7;
        dstOff[t] = (unsigned)((w * 2 + t) * 1024);
        srcK[t] = (size_t)row * ld + (size_t)((cb ^ (row & 7)) * 8);
        srcV[t] = (size_t)row * L_SEQ + (size_t)((cb ^ (row & 7)) * 8);
    }
    char* ksBase = (char*)Ks;
    char* vsBase = (char*)Vs;
    char* PlB = (char*)Pl + w * 2048;

    // prologue: stage tile 0 (both sub-tiles) into dbuf slot 0
#pragma unroll
    for (int sub = 0; sub < 2; ++sub)
#pragma unroll
        for (int t = 0; t < 2; ++t) {
            gld16(Kp + (size_t)sub * 64 * ld + srcK[t], ksBase + sub * SUB + dstOff[t]);
            gld16(VtH + sub * 64 + srcV[t], vsBase + sub * SUB + dstOff[t]);
        }
    __syncthreads();

    float mrow[4];
    f32x4 lacc = {};
    f32x4 oacc[4] = {};
#pragma unroll
    for (int r = 0; r < 4; ++r) mrow[r] = -1e30f;

    float2 cskN[8];
#pragma unroll
    for (int kb = 0; kb < 8; ++kb) cskN[kb] = CS[kb * 16 + u];

    for (int kt = 0; kt < NT; ++kt) {
        const int cur = kt & 1;
        const char* kCur = ksBase + cur * BUF;
        const char* vCur = vsBase + cur * BUF;

        float ck8[8], sk8[8];
#pragma unroll
        for (int kb = 0; kb < 8; ++kb) { ck8[kb] = cskN[kb].x; sk8[kb] = cskN[kb].y; }
        if (kt + 1 < NT) {
#pragma unroll
            for (int kb = 0; kb < 8; ++kb)
                cskN[kb] = CS[(kt + 1) * 128 + kb * 16 + u];
        }

        // prefetch next 128-key tile
        if (kt + 1 < NT) {
            const u16* Kn = Kp + (size_t)(kt + 1) * 128 * ld;
            const u16* Vn = VtH + (size_t)(kt + 1) * 128;
            char* kN = ksBase + (cur ^ 1) * BUF;
            char* vN = vsBase + (cur ^ 1) * BUF;
#pragma unroll
            for (int sub = 0; sub < 2; ++sub)
#pragma unroll
                for (int t = 0; t < 2; ++t) {
                    gld16(Kn + (size_t)sub * 64 * ld + srcK[t], kN + sub * SUB + dstOff[t]);
                    gld16(Vn + sub * 64 + srcV[t], vN + sub * SUB + dstOff[t]);
                }
        }

        // ---- S = Q K^T over both sub-tiles (8 kb) ----
        f32x4 sf[8];
        const int x0 = (g * 16) ^ ((u & 7) << 4);
#pragma unroll
        for (int kb = 0; kb < 8; ++kb) {
            const char* kp = kCur + (kb >> 2) * SUB + ((kb & 3) * 16 + u) * 128;
            s16x8 b0 = *(const s16x8*)(kp + x0);
            s16x8 b1 = *(const s16x8*)(kp + (x0 ^ 64));
            f32x4 z = {};
            z = __builtin_amdgcn_mfma_f32_16x16x32_bf16(aq0, b0, z, 0, 0, 0);
            sf[kb] = __builtin_amdgcn_mfma_f32_16x16x32_bf16(aq1, b1, z, 0, 0, 0);
        }

        // ---- bias + lane-local max over 8 kb ----
        float sv[8][4], tmax[4];
#pragma unroll
        for (int r = 0; r < 4; ++r) tmax[r] = -1e30f;
#pragma unroll
        for (int kb = 0; kb < 8; ++kb)
#pragma unroll
            for (int r = 0; r < 4; ++r) {
                float xv = sf[kb][r] * SC2 + gcq[r] * ck8[kb] + gsq[r] * sk8[kb];
                sv[kb][r] = xv;
                tmax[r] = fmaxf(tmax[r], xv);
            }

        // ---- one deferred-max check per 128 keys ----
        bool need = false;
#pragma unroll
        for (int r = 0; r < 4; ++r) need |= (tmax[r] > mrow[r] + 4.0f);
        if (__any(need)) {
            float scl[4];
#pragma unroll
            for (int r = 0; r < 4; ++r) {
                float t = tmax[r];
#pragma unroll
                for (int msk = 1; msk <= 8; msk <<= 1)
                    t = fmaxf(t, __shfl_xor(t, msk));
                float mn = fmaxf(mrow[r], t);
                scl[r] = __builtin_amdgcn_exp2f(mrow[r] - mn);
                mrow[r] = mn;
            }
#pragma unroll
            for (int db = 0; db < 4; ++db)
#pragma unroll
                for (int r = 0; r < 4; ++r)
                    oacc[db][r] *= scl[r];
#pragma unroll
            for (int r = 0; r < 4; ++r) lacc[r] *= scl[r];
        }

        // ---- per sub-tile: P -> LDS, then PV (verified layouts) ----
#pragma unroll
        for (int sub = 0; sub < 2; ++sub) {
#pragma unroll
            for (int kbl = 0; kbl < 4; ++kbl) {
                const int kb = sub * 4 + kbl;
#pragma unroll
                for (int r = 0; r < 4; ++r) {
                    float p = __builtin_amdgcn_exp2f(sv[kb][r] - mrow[r]);
                    int prow = g * 4 + r;
                    int pb = prow * 128 + (kbl * 16 + u) * 2;
                    pb ^= (prow & 7) << 4;
                    *(u16*)(PlB + pb) = f2b(p);
                }
            }
            const char* vSub = vCur + sub * SUB;
#pragma unroll
            for (int ks = 0; ks < 2; ++ks) {
                const int xv = (ks * 64 + g * 16) ^ ((u & 7) << 4);
                s16x8 pa = *(const s16x8*)(PlB + u * 128 + xv);
                lacc = __builtin_amdgcn_mfma_f32_16x16x32_bf16(pa, vone, lacc, 0, 0, 0);
#pragma unroll
                for (int db = 0; db < 4; ++db) {
                    s16x8 bv = *(const s16x8*)(vSub + (db * 16 + u) * 128 + xv);
                    oacc[db] = __builtin_amdgcn_mfma_f32_16x16x32_bf16(pa, bv, oacc[db], 0, 0, 0);
                }
            }
        }
        __syncthreads();
    }

#pragma unroll
    for (int db = 0; db < 4; ++db)
#pragma unroll
        for (int r = 0; r < 4; ++r) {
            int qr = qb + w * 16 + g * 4 + r;
            int col = h * 64 + db * 16 + u;
            Oout[(size_t)qr * DMODEL + col] = f2b(oacc[db][r] / lacc[r]);
        }
}

extern "C" void kernel_launch(void* const* d_in, const int* in_sizes, int n_in,
                              void* d_out, int out_size, void* d_ws, size_t ws_size,
                              hipStream_t stream) {
    const float* x  = (const float*)d_in[0];
    const float* Wq = (const float*)d_in[1];
    const float* bq = (const float*)d_in[2];
    const float* Wk = (const float*)d_in[3];
    const float* bk = (const float*)d_in[4];
    const float* Wv = (const float*)d_in[5];
    const float* bv = (const float*)d_in[6];
    const float* Wo = (const float*)d_in[7];
    const float* bo = (const float*)d_in[8];
    const float* Wp = (const float*)d_in[9];
    const float* bp = (const float*)d_in[10];
    const float* gamma = (const float*)d_in[11];
    float* out = (float*)d_out;

    char* ws = (char*)d_ws;
    u16* xb = (u16*)ws;   ws += (size_t)L_SEQ * DMODEL * 2;
    u16* wqb = (u16*)ws;  ws += (size_t)DMODEL * DMODEL * 2;
    u16* wkb = (u16*)ws;  ws += (size_t)DMODEL * DMODEL * 2;
    u16* wvb = (u16*)ws;  ws += (size_t)DMODEL * DMODEL * 2;
    u16* wob = (u16*)ws;  ws += (size_t)DMODEL * DMODEL * 2;
    u16* qkv = (u16*)ws;  ws += (size_t)L_SEQ * 3 * DMODEL * 2;
    u16* attnb = (u16*)ws; ws += (size_t)L_SEQ * DMODEL * 2;
    u16* VtG = (u16*)ws;  ws += (size_t)DMODEL * L_SEQ * 2;
    float2* CSph = (float2*)ws; ws += (size_t)NHEAD * L_SEQ * 8;

    // converts (3072 blocks) + phase (512 blocks)
    k_pre<<<3072 + 512, 256, 0, stream>>>(x, Wq, Wk, Wv, Wo, xb, wqb, wkb, wvb, wob,
                                          Wp, bp, CSph);

    // fused QKV projection: Q,K -> qkv bf16; V -> VtG transposed (verified R10)
    k_gemm64<0><<<dim3(16, 48), 256, 0, stream>>>(xb, wqb, wkb, wvb, bq, bk, bv,
                                                  (void*)qkv, VtG, 3 * DMODEL, DMODEL);

    // attention (KVBLK=128, two verified sub-tiles per iteration)
    k_attn<<<dim3(L_SEQ / 64, NHEAD), 256, 0, stream>>>(qkv, VtG, CSph, gamma, attnb);

    // output projection -> d_out f32
    k_gemm64<1><<<dim3(16, 16), 256, 0, stream>>>(attnb, wob, wob, wob, bo, bo, bo,
                                                  (void*)out, nullptr, DMODEL, DMODEL);
}